// Round 1
// baseline (237.375 us; speedup 1.0000x reference)
//
#include <hip/hip_runtime.h>
#include <stdint.h>

#define A_NUM 9
#define H_FM 50
#define W_FM 80
#define N_ANCH (A_NUM * H_FM * W_FM)   // 36000
#define NSORT 65536
#define PRE_NMS_N 6000
#define POST_NMS_N 300
#define NMS_TH 0.7f
#define MASK_W 94            // ceil(6000/64)
#define MASK_STRIDE 96

typedef unsigned long long ull;

// base anchor widths/heights (verified vs generate_anchors with np.round half-to-even)
__constant__ float c_aw[9] = {184.f,368.f,736.f,128.f,256.f,512.f, 88.f,176.f,352.f};
__constant__ float c_ah[9] = { 96.f,192.f,384.f,128.f,256.f,512.f,176.f,352.f,704.f};

__device__ float4 g_boxes[N_ANCH];
__device__ ull    g_keys[NSORT];
__device__ float4 g_props[PRE_NMS_N];
__device__ ull    g_mask[(size_t)PRE_NMS_N * MASK_STRIDE];
__device__ ull    g_dead[MASK_STRIDE];
__device__ int    g_kept_idx[POST_NMS_N];
__device__ int    g_kept_count;

// ---------------- decode + key build ----------------
__global__ void k_decode(const float* __restrict__ scores,
                         const float* __restrict__ deltas,
                         const float* __restrict__ iminfo) {
    int i = blockIdx.x * blockDim.x + threadIdx.x;
    if (i < MASK_STRIDE) g_dead[i] = 0ULL;
    if (i >= NSORT) return;
    if (i >= N_ANCH) { g_keys[i] = ~0ULL; return; }

    int a    = i % A_NUM;
    int cell = i / A_NUM;
    int x    = cell % W_FM;
    int y    = cell / W_FM;
    const int hw = H_FM * W_FM;

    float sc = scores[(A_NUM + a) * hw + cell];

    int dbase = (a * 4) * hw + cell;
    float d0 = deltas[dbase];
    float d1 = deltas[dbase + hw];
    float d2 = deltas[dbase + 2 * hw];
    float d3 = deltas[dbase + 3 * hw];
    d2 = fminf(fmaxf(d2, -10.f), 10.f);
    d3 = fminf(fmaxf(d3, -10.f), 10.f);

    float aw = c_aw[a], ah = c_ah[a];
    // all base anchors have ctr 7.5 -> x1 + 0.5*aw == 8 (+16*x)
    float acx = (float)(x * 16 + 8);
    float acy = (float)(y * 16 + 8);

    float pcx = d0 * aw + acx;
    float pcy = d1 * ah + acy;
    float pw  = expf(d2) * aw;
    float ph  = expf(d3) * ah;

    float x1 = pcx - 0.5f * pw;
    float y1 = pcy - 0.5f * ph;
    float x2 = pcx + 0.5f * pw;
    float y2 = pcy + 0.5f * ph;

    float imh = iminfo[0], imw = iminfo[1], ims = iminfo[2];
    x1 = fminf(fmaxf(x1, 0.f), imw - 1.f);
    y1 = fminf(fmaxf(y1, 0.f), imh - 1.f);
    x2 = fminf(fmaxf(x2, 0.f), imw - 1.f);
    y2 = fminf(fmaxf(y2, 0.f), imh - 1.f);

    float wsz = x2 - x1 + 1.f;
    float hsz = y2 - y1 + 1.f;
    float minsz = 16.f * ims;
    bool valid = (wsz >= minsz) && (hsz >= minsz);

    g_boxes[i] = make_float4(x1, y1, x2, y2);

    unsigned int u   = __float_as_uint(sc);
    unsigned int asc = (u & 0x80000000u) ? ~u : (u | 0x80000000u);
    unsigned int dk  = ~asc;                 // ascending dk == descending score
    if (!valid) dk = 0xFF800000u;            // == key of -inf score
    g_keys[i] = ((ull)dk << 32) | (unsigned int)i;
}

// ---------------- bitonic sort: local full sort of 2048-chunks ----------------
__global__ __launch_bounds__(1024) void k_sort_local() {
    __shared__ ull s[2048];
    int t = threadIdx.x;
    int base = blockIdx.x * 2048;
    s[t]        = g_keys[base + t];
    s[t + 1024] = g_keys[base + t + 1024];
    __syncthreads();
    for (int k = 2; k <= 2048; k <<= 1) {
        for (int j = k >> 1; j >= 1; j >>= 1) {
            int i = ((t & ~(j - 1)) << 1) | (t & (j - 1));
            int p = i | j;
            bool up = (((base + i) & k) == 0);
            ull a = s[i], b = s[p];
            if ((a > b) == up) { s[i] = b; s[p] = a; }
            __syncthreads();
        }
    }
    g_keys[base + t]        = s[t];
    g_keys[base + t + 1024] = s[t + 1024];
}

// ---------------- bitonic sort: strided (column) substages j>=2048 ----------------
// Each thread owns the 32 elements {g + m*2048}. Templated K -> fully static reg indexing.
template <int K>
__global__ void k_merge_col() {
    int g = blockIdx.x * blockDim.x + threadIdx.x;   // 0..2047
    ull v[32];
#pragma unroll
    for (int m = 0; m < 32; ++m) v[m] = g_keys[g + (m << 11)];
#pragma unroll
    for (int j = K >> 1; j >= 2048; j >>= 1) {
        const int jj = j >> 11;
#pragma unroll
        for (int m = 0; m < 32; ++m) {
            if ((m & jj) == 0) {
                const int p = m | jj;
                bool up = (((m << 11) & K) == 0);
                ull a = v[m], b = v[p];
                if ((a > b) == up) { v[m] = b; v[p] = a; }
            }
        }
    }
#pragma unroll
    for (int m = 0; m < 32; ++m) g_keys[g + (m << 11)] = v[m];
}

// ---------------- bitonic sort: local merge substages j<=1024 for stage k ----------------
__global__ __launch_bounds__(1024) void k_merge_local(int k) {
    __shared__ ull s[2048];
    int t = threadIdx.x;
    int base = blockIdx.x * 2048;
    s[t]        = g_keys[base + t];
    s[t + 1024] = g_keys[base + t + 1024];
    __syncthreads();
    for (int j = 1024; j >= 1; j >>= 1) {
        int i = ((t & ~(j - 1)) << 1) | (t & (j - 1));
        int p = i | j;
        bool up = (((base + i) & k) == 0);
        ull a = s[i], b = s[p];
        if ((a > b) == up) { s[i] = b; s[p] = a; }
        __syncthreads();
    }
    g_keys[base + t]        = s[t];
    g_keys[base + t + 1024] = s[t + 1024];
}

// ---------------- gather props + initial dead mask ----------------
__global__ void k_prep() {
    int r = blockIdx.x * blockDim.x + threadIdx.x;
    if (r >= PRE_NMS_N) return;
    ull key = g_keys[r];
    unsigned int dk = (unsigned int)(key >> 32);
    if (dk < 0xFF800000u) {                      // finite score (not -inf, not pad)
        unsigned int idx = (unsigned int)key;
        g_props[r] = g_boxes[idx];
    } else {
        g_props[r] = make_float4(0.f, 0.f, 0.f, 0.f);
        atomicOr(&g_dead[r >> 6], 1ULL << (r & 63));
    }
}

// ---------------- IoU suppression mask matrix ----------------
// grid (24, 94), block 256: blockIdx.x -> 4 mask words (256 j's), blockIdx.y -> 64 rows
__global__ void k_mask() {
    __shared__ float4 sj[256];
    int tid = threadIdx.x;
    int jbase = blockIdx.x * 256;
    int jj = jbase + tid;
    sj[tid] = (jj < PRE_NMS_N) ? g_props[jj] : make_float4(0.f, 0.f, 0.f, 0.f);
    __syncthreads();

    int li = tid & 63;
    int wl = tid >> 6;                       // 0..3
    int i  = blockIdx.y * 64 + li;
    int w  = blockIdx.x * 4 + wl;
    if (i >= PRE_NMS_N || w >= MASK_W) return;

    float4 bi = g_props[i];
    float ai = (bi.z - bi.x + 1.f) * (bi.w - bi.y + 1.f);
    ull bits = 0;
    int jstart = w * 64;
    int lbase = jstart - jbase;              // 0,64,128,192
    for (int b = 0; b < 64; ++b) {
        int j = jstart + b;
        if (j <= i || j >= PRE_NMS_N) continue;
        float4 bj = sj[lbase + b];
        float aj = (bj.z - bj.x + 1.f) * (bj.w - bj.y + 1.f);
        float iw = fminf(bi.z, bj.z) - fmaxf(bi.x, bj.x) + 1.f;
        float ih = fminf(bi.w, bj.w) - fmaxf(bi.y, bj.y) + 1.f;
        iw = fmaxf(iw, 0.f);
        ih = fmaxf(ih, 0.f);
        float inter = iw * ih;
        float iou = inter / (ai + aj - inter);
        if (iou > NMS_TH) bits |= (1ULL << b);
    }
    g_mask[(size_t)i * MASK_STRIDE + w] = bits;
}

// ---------------- sequential greedy scan (1 wave), early exit at 300 kept ----------------
__global__ void k_scan() {
    int lane = threadIdx.x;
    ull rm0 = g_dead[lane];                              // words 0..63
    ull rm1 = (lane < MASK_W - 64) ? g_dead[64 + lane] : 0ULL;  // words 64..93
    int kc = 0;
    for (int w = 0; w < MASK_W; ++w) {
        ull cur = (w < 64) ? __shfl(rm0, w) : __shfl(rm1, w - 64);
        int bmax = PRE_NMS_N - w * 64;
        if (bmax > 64) bmax = 64;
        for (int b = 0; b < bmax; ++b) {
            if (((cur >> b) & 1ULL) == 0ULL) {
                int i = w * 64 + b;
                if (lane == 0) g_kept_idx[kc] = i;
                kc++;
                if (kc == POST_NMS_N) goto done;
                const ull* row = g_mask + (size_t)i * MASK_STRIDE;
                rm0 |= row[lane];
                if (lane < MASK_W - 64) rm1 |= row[64 + lane];
                cur = (w < 64) ? __shfl(rm0, w) : __shfl(rm1, w - 64);
            }
        }
    }
done:
    if (lane == 0) g_kept_count = kc;
}

// ---------------- write output ----------------
__global__ void k_out(float* __restrict__ out) {
    int r = blockIdx.x * blockDim.x + threadIdx.x;
    if (r >= POST_NMS_N) return;
    int kc = g_kept_count;
    float4 p = make_float4(0.f, 0.f, 0.f, 0.f);
    if (r < kc) p = g_props[g_kept_idx[r]];
    out[r * 5 + 0] = 0.f;
    out[r * 5 + 1] = p.x;
    out[r * 5 + 2] = p.y;
    out[r * 5 + 3] = p.z;
    out[r * 5 + 4] = p.w;
}

extern "C" void kernel_launch(void* const* d_in, const int* in_sizes, int n_in,
                              void* d_out, int out_size, void* d_ws, size_t ws_size,
                              hipStream_t stream) {
    const float* scores = (const float*)d_in[0];
    const float* deltas = (const float*)d_in[1];
    const float* iminfo = (const float*)d_in[2];
    float* out = (float*)d_out;

    k_decode<<<NSORT / 256, 256, 0, stream>>>(scores, deltas, iminfo);

    k_sort_local<<<32, 1024, 0, stream>>>();
    k_merge_col<4096><<<8, 256, 0, stream>>>();
    k_merge_local<<<32, 1024, 0, stream>>>(4096);
    k_merge_col<8192><<<8, 256, 0, stream>>>();
    k_merge_local<<<32, 1024, 0, stream>>>(8192);
    k_merge_col<16384><<<8, 256, 0, stream>>>();
    k_merge_local<<<32, 1024, 0, stream>>>(16384);
    k_merge_col<32768><<<8, 256, 0, stream>>>();
    k_merge_local<<<32, 1024, 0, stream>>>(32768);
    k_merge_col<65536><<<8, 256, 0, stream>>>();
    k_merge_local<<<32, 1024, 0, stream>>>(65536);

    k_prep<<<(PRE_NMS_N + 255) / 256, 256, 0, stream>>>();
    k_mask<<<dim3(24, 94), 256, 0, stream>>>();
    k_scan<<<1, 64, 0, stream>>>();
    k_out<<<2, 256, 0, stream>>>(out);
}